// Round 13
// baseline (40.970 us; speedup 1.0000x reference)
//
#include <hip/hip_runtime.h>
#include <math.h>

#define BATCH_C 16384
#define UPW 128   // units per wave in the dense pool kernel

typedef float f32x4  __attribute__((ext_vector_type(4)));
typedef f32x4 __attribute__((aligned(4))) f32x4_u;   // dword-aligned vector load
typedef float f32x16 __attribute__((ext_vector_type(16)));
typedef short s16x8  __attribute__((ext_vector_type(8)));
typedef union { unsigned u[4]; s16x8 v; } abfrag_t;

// RNE fp32->bf16 (used only for the B/weight fragments, built once per block)
static __device__ inline unsigned rlo_f(float x) {
    unsigned u = __float_as_uint(x);
    return (u + 0x7fffu + ((u >> 16) & 1u)) >> 16;
}

// ---------------------------------------------------------------------------
// Kernel 1 (DENSE POOL): per-unit MLP (9->64, ReLU) + segment sum via MFMA
// over dense 32-unit windows (static addressing, exact 4 windows/wave).
// Boundaries recovered from ballot(seg[u]!=seg[u-1]); interior segments flush
// straight to pooled[] (exactly-once); the wave's first/last segments write
// partials pF/pL[wave][ch]. seg_starts generation is folded in (start[b] =
// first unit with seg>=b), since the seg values are already in registers.
// bf16 3-term split (truncated hi AND truncated lo): dropped error ~2^-15.4
// per product -> pooled absmax ~3e-4 (threshold 1.3e-3).
// ---------------------------------------------------------------------------
__global__ __launch_bounds__(256, 4) void pool_dense(
    const float* __restrict__ lfeats, const float* __restrict__ rfeats,
    const int* __restrict__ lseg, const int* __restrict__ rseg,
    int* __restrict__ lstart, int* __restrict__ rstart,
    const float* __restrict__ W1, const float* __restrict__ b1,
    float* __restrict__ pooled,
    float* __restrict__ pFl, float* __restrict__ pLl,
    float* __restrict__ pFr, float* __restrict__ pLr,
    int n)
{
    const int lane = threadIdx.x & 63;
    const int wv   = threadIdx.x >> 6;
    const int side = blockIdx.y;
    const int wgid = blockIdx.x * 4 + wv;
    const int lo   = wgid * UPW;
    const int r    = lane & 31;
    const int hh   = lane >> 5;
    const int nmax = n - 1;
    const int ofs1 = hh ? 5 : 4;
    const unsigned khi = hh ? 0u : 0xffffffffu;
    const int sideofs = side * 64;

    const float* __restrict__ feats = side ? rfeats : lfeats;
    const int*   __restrict__ sg    = side ? rseg : lseg;
    int* __restrict__ stw  = side ? rstart : lstart;
    float* __restrict__ pFs = side ? pFr : pFl;
    float* __restrict__ pLs = side ? pLr : pLl;

    // ---- stage B fragments (W1 cols + bias row at k=9, hi/lo RNE) ----
    __shared__ __align__(16) short sBh[2][32][16];
    __shared__ __align__(16) short sBl[2][32][16];
    {
        const int t = threadIdx.x;
        const int tile = t >> 7, col = (t >> 2) & 31, k0 = (t & 3) * 4;
        const int ch = tile * 32 + col;
#pragma unroll
        for (int q = 0; q < 4; ++q) {
            const int k = k0 + q;
            float v = 0.0f;
            if (k < 9) v = W1[k * 64 + ch];
            else if (k == 9) v = b1[ch];
            unsigned hi = rlo_f(v);
            float d = v - __uint_as_float(hi << 16);
            sBh[tile][col][k] = (short)hi;
            sBl[tile][col][k] = (short)rlo_f(d);
        }
    }
    __syncthreads();
    const s16x8 bh0 = *reinterpret_cast<const s16x8*>(&sBh[0][r][hh * 8]);
    const s16x8 bh1 = *reinterpret_cast<const s16x8*>(&sBh[1][r][hh * 8]);
    const s16x8 bl0 = *reinterpret_cast<const s16x8*>(&sBl[0][r][hh * 8]);
    const s16x8 bl1 = *reinterpret_cast<const s16x8*>(&sBl[1][r][hh * 8]);
    const f32x16 kZ = (f32x16)0.0f;

    // ---- seg values for this wave's 128 units + folded seg_starts ----
    const int u0 = lo + lane, u1 = lo + 64 + lane;
    const int s0v = sg[u0 > nmax ? nmax : u0];
    const int s1v = sg[u1 > nmax ? nmax : u1];
    const int p0v = sg[u0 > 0 ? u0 - 1 : 0];
    const int p1v = sg[(u1 - 1) > nmax ? nmax : (u1 - 1)];
    {   // start[b] = first i with seg[i] >= b (each b written exactly once)
        int pe0 = (u0 == 0) ? -1 : p0v;
        for (int b = pe0 + 1; b <= s0v; ++b) stw[b] = u0;
        for (int b = p1v + 1; b <= s1v; ++b) stw[b] = u1;
        if (u1 == nmax) for (int b = s1v + 1; b <= BATCH_C; ++b) stw[b] = n;
    }
    // boundary bitmasks (bit = new segment starts at that row; global row 0
    // of the range excluded -- handled by the pF/pL partial mechanism)
    const bool bd0 = (lane != 0) && (s0v != p0v);
    const bool bd1 = (s1v != p1v);
    const unsigned long long mm0 = __ballot(bd0);
    const unsigned long long mm1 = __ballot(bd1);
    const unsigned wm0 = (unsigned)mm0, wm1 = (unsigned)(mm0 >> 32);
    const unsigned wm2 = (unsigned)mm1, wm3 = (unsigned)(mm1 >> 32);

#define FETCHD(POS, Q0,Q1,Q2,Q3,Q4,Q5,Q6,Q7) do {                         \
        int uu_ = (POS) + r; if (uu_ > nmax) uu_ = nmax;                  \
        const float* fp_ = feats + (size_t)uu_ * 9;                       \
        f32x4 x0_ = *reinterpret_cast<const f32x4_u*>(fp_);               \
        f32x4 x1_ = *reinterpret_cast<const f32x4_u*>(fp_ + ofs1);        \
        Q0 = hh ? x1_.w : x0_.x;                                          \
        Q1 = x0_.y; Q2 = x0_.z; Q3 = x0_.w;                               \
        Q4 = x1_.x; Q5 = x1_.y; Q6 = x1_.z; Q7 = x1_.w;                   \
    } while (0)

// truncated-hi + truncated-lo bf16 split (no validity masking needed)
#define CONVD(Q0,Q1,Q2,Q3,Q4,Q5,Q6,Q7, AH, AL) do {                       \
    unsigned u0_=__float_as_uint(Q0), u1_=__float_as_uint(Q1),            \
             u2_=__float_as_uint(Q2), u3_=__float_as_uint(Q3),            \
             u4_=__float_as_uint(Q4), u5_=__float_as_uint(Q5),            \
             u6_=__float_as_uint(Q6), u7_=__float_as_uint(Q7);            \
    float d0_=Q0-__uint_as_float(u0_&0xffff0000u);                        \
    float d1_=Q1-__uint_as_float(u1_&0xffff0000u);                        \
    float d2_=Q2-__uint_as_float(u2_&0xffff0000u);                        \
    float d3_=Q3-__uint_as_float(u3_&0xffff0000u);                        \
    float d4_=Q4-__uint_as_float(u4_&0xffff0000u);                        \
    float d5_=Q5-__uint_as_float(u5_&0xffff0000u);                        \
    float d6_=Q6-__uint_as_float(u6_&0xffff0000u);                        \
    float d7_=Q7-__uint_as_float(u7_&0xffff0000u);                        \
    AH.u[0] = hh ? ((u0_>>16)|0x3F800000u) : ((u0_>>16)|(u1_&0xffff0000u));\
    AL.u[0] = hh ? (__float_as_uint(d0_)>>16)                             \
                 : ((__float_as_uint(d0_)>>16)|(__float_as_uint(d1_)&0xffff0000u));\
    AH.u[1] = khi & ((u2_>>16)|(u3_&0xffff0000u));                        \
    AL.u[1] = khi & ((__float_as_uint(d2_)>>16)|(__float_as_uint(d3_)&0xffff0000u));\
    AH.u[2] = khi & ((u4_>>16)|(u5_&0xffff0000u));                        \
    AL.u[2] = khi & ((__float_as_uint(d4_)>>16)|(__float_as_uint(d5_)&0xffff0000u));\
    AH.u[3] = khi & ((u6_>>16)|(u7_&0xffff0000u));                        \
    AL.u[3] = khi & ((__float_as_uint(d6_)>>16)|(__float_as_uint(d7_)&0xffff0000u));\
} while (0)

#define MFMAC(AH, AL) do {                                                \
    c0_ = __builtin_amdgcn_mfma_f32_32x32x16_bf16(AL.v, bh0, kZ, 0,0,0);  \
    c0_ = __builtin_amdgcn_mfma_f32_32x32x16_bf16(AH.v, bl0, c0_, 0,0,0); \
    c0_ = __builtin_amdgcn_mfma_f32_32x32x16_bf16(AH.v, bh0, c0_, 0,0,0); \
    c1_ = __builtin_amdgcn_mfma_f32_32x32x16_bf16(AL.v, bh1, kZ, 0,0,0);  \
    c1_ = __builtin_amdgcn_mfma_f32_32x32x16_bf16(AH.v, bl1, c1_, 0,0,0); \
    c1_ = __builtin_amdgcn_mfma_f32_32x32x16_bf16(AH.v, bh1, c1_, 0,0,0); \
} while (0)

#define FULLSUM do {                                                      \
    float sA_=0.f,sB_=0.f,sC_=0.f,sD_=0.f,tA_=0.f,tB_=0.f,tC_=0.f,tD_=0.f;\
    _Pragma("unroll")                                                     \
    for (int t_=0; t_<4; ++t_) {                                          \
        sA_+=fmaxf(c0_[t_],0.f);    sB_+=fmaxf(c0_[t_+4],0.f);            \
        sC_+=fmaxf(c0_[t_+8],0.f);  sD_+=fmaxf(c0_[t_+12],0.f);           \
        tA_+=fmaxf(c1_[t_],0.f);    tB_+=fmaxf(c1_[t_+4],0.f);            \
        tC_+=fmaxf(c1_[t_+8],0.f);  tD_+=fmaxf(c1_[t_+12],0.f);           \
    }                                                                     \
    acc0 += (sA_+sB_)+(sC_+sD_);                                          \
    acc1 += (tA_+tB_)+(tC_+tD_);                                          \
} while (0)

#define RANGESUM(LOV, HIV) do {                                           \
    _Pragma("unroll")                                                     \
    for (int t_=0; t_<16; ++t_) {                                         \
        const int rowt_ = (t_&3) + 8*(t_>>2) + 4*hh;                      \
        const bool in_ = (rowt_ >= (LOV)) && (rowt_ < (HIV));             \
        acc0 += in_ ? fmaxf(c0_[t_],0.f) : 0.f;                           \
        acc1 += in_ ? fmaxf(c1_[t_],0.f) : 0.f;                           \
    }                                                                     \
} while (0)

#define FLUSHSEG(BP, BN) do {                                             \
    float fs0_ = acc0 + __shfl_xor(acc0, 32, 64);                         \
    float fs1_ = acc1 + __shfl_xor(acc1, 32, 64);                         \
    float ov_ = (lane >= 32) ? fs1_ : fs0_;                               \
    if (nflush == 0) pFs[(size_t)wgid*64 + lane] = ov_;                   \
    else pooled[(size_t)(BP)*128 + sideofs + lane] = ov_;                 \
    ++nflush; acc0 = 0.f; acc1 = 0.f;                                     \
    for (int e_=(BP)+1; e_<(BN); ++e_)                                    \
        pooled[(size_t)e_*128 + sideofs + lane] = 0.0f;                   \
} while (0)

#define WINDOW(WK, MASKV, Q0,Q1,Q2,Q3,Q4,Q5,Q6,Q7, DOPF) do {             \
    abfrag_t AH_, AL_;                                                    \
    CONVD(Q0,Q1,Q2,Q3,Q4,Q5,Q6,Q7, AH_, AL_);                             \
    f32x16 c0_, c1_;                                                      \
    MFMAC(AH_, AL_);                                                      \
    if (DOPF) { FETCHD(lo + ((WK)+2)*32, Q0,Q1,Q2,Q3,Q4,Q5,Q6,Q7); }      \
    unsigned bm_ = (MASKV);                                               \
    if (bm_ == 0u) { FULLSUM; }                                           \
    else {                                                                \
        int prev_ = 0;                                                    \
        while (bm_) {                                                     \
            int p_ = __builtin_ctz(bm_); bm_ &= bm_ - 1u;                 \
            RANGESUM(prev_, p_);                                          \
            int gi_ = (WK)*32 + p_;                                       \
            int bp_ = (gi_ - 1 < 64) ? __shfl(s0v, gi_ - 1, 64)           \
                                     : __shfl(s1v, gi_ - 65, 64);         \
            int bn_ = (gi_ < 64) ? __shfl(s0v, gi_, 64)                   \
                                 : __shfl(s1v, gi_ - 64, 64);             \
            bp_ = __builtin_amdgcn_readfirstlane(bp_);                    \
            bn_ = __builtin_amdgcn_readfirstlane(bn_);                    \
            FLUSHSEG(bp_, bn_);                                           \
            prev_ = p_;                                                   \
        }                                                                 \
        RANGESUM(prev_, 32);                                              \
    }                                                                     \
} while (0)

    float a0,a1,a2,a3,a4,a5,a6,a7;   // window reg set A (even windows)
    float b0v,b1v,b2v,b3v,b4v,b5v,b6v,b7v;  // set B (odd windows)
    FETCHD(lo,      a0,a1,a2,a3,a4,a5,a6,a7);
    FETCHD(lo + 32, b0v,b1v,b2v,b3v,b4v,b5v,b6v,b7v);

    float acc0 = 0.f, acc1 = 0.f;
    int nflush = 0;

    WINDOW(0, wm0, a0,a1,a2,a3,a4,a5,a6,a7, 1);
    WINDOW(1, wm1, b0v,b1v,b2v,b3v,b4v,b5v,b6v,b7v, 1);
    WINDOW(2, wm2, a0,a1,a2,a3,a4,a5,a6,a7, 0);
    WINDOW(3, wm3, b0v,b1v,b2v,b3v,b4v,b5v,b6v,b7v, 0);

    // epilogue: last segment's in-range partial (and pF if no flush happened)
    {
        float fm0 = acc0 + __shfl_xor(acc0, 32, 64);
        float fm1 = acc1 + __shfl_xor(acc1, 32, 64);
        float fov = (lane >= 32) ? fm1 : fm0;
        pLs[(size_t)wgid*64 + lane] = fov;
        if (nflush == 0) pFs[(size_t)wgid*64 + lane] = fov;
    }
#undef WINDOW
#undef FLUSHSEG
#undef RANGESUM
#undef FULLSUM
#undef MFMAC
#undef CONVD
#undef FETCHD
}

// ---------------------------------------------------------------------------
// Kernel 2 (FIXUP + HEAD): reconstruct edge rows from partials (fixed-order
// sums -> deterministic), read interior rows from pooled, then head MLP.
// Row b (per side): wa = start[b]>>7; owned-by-fixup iff start[b]%128==0 or
// end[b] > wa*128+127; else phase-1 wrote pooled[b] (incl. interior empties=0).
// ---------------------------------------------------------------------------
__global__ __launch_bounds__(256) void head2_kernel(
    const int* __restrict__ lstart, const int* __restrict__ rstart,
    const int* __restrict__ lseg, const int* __restrict__ rseg,
    const float* __restrict__ pooled,
    const float* __restrict__ pFl, const float* __restrict__ pLl,
    const float* __restrict__ pFr, const float* __restrict__ pLr,
    const float* __restrict__ Wc1, const float* __restrict__ bc1,
    const float* __restrict__ Wc2, const float* __restrict__ bc2,
    float* __restrict__ out)
{
    const int lane = threadIdx.x & 63;
    const int wv   = threadIdx.x >> 6;
    const int hh   = lane >> 5;
    const int S0   = (blockIdx.x * 4 + wv) * 2;

    __shared__ __align__(16) float rowbuf[4][2][128];

    for (int rowi = 0; rowi < 2; ++rowi) {
        const int b = S0 + rowi;
#pragma unroll
        for (int sd = 0; sd < 2; ++sd) {
            const int* st = sd ? rstart : lstart;
            const int* sgp = sd ? rseg : lseg;
            const float* pFp = sd ? pFr : pFl;
            const float* pLp = sd ? pLr : pLl;
            const int sb = st[b];
            const int se = st[b + 1];
            const int wa = sb >> 7;
            const bool owned = ((sb & 127) == 0) || (se > (wa << 7) + 127);
            float v;
            if (owned) {
                v = 0.0f;
                const int wb = (se > sb) ? ((se - 1) >> 7) : (wa - 1);
                for (int w = wa; w <= wb; ++w) {
                    const int key = sgp[w << 7];
                    const float* src = (key == b) ? pFp : pLp;
                    v += src[(size_t)w * 64 + lane];
                }
            } else {
                v = pooled[(size_t)b * 128 + sd * 64 + lane];
            }
            rowbuf[wv][rowi][sd * 64 + lane] = v;
        }
    }
    // same-wave RAW on per-wave rowbuf
    asm volatile("s_waitcnt lgkmcnt(0)" ::: "memory");

    {   // head: half-wave per row; lane j = hidden unit; Wc1 column coalesced
        const int j = lane & 31;
        const float* __restrict__ rb = &rowbuf[wv][hh][0];
        const float* __restrict__ wc = Wc1 + j;

        float accA = bc1[j], accB = 0.0f;
#pragma unroll 8
        for (int k = 0; k < 128; k += 4) {
            f32x4 v = *reinterpret_cast<const f32x4*>(rb + k);
            accA = fmaf(v.x, wc[(k + 0) * 32], accA);
            accB = fmaf(v.y, wc[(k + 1) * 32], accB);
            accA = fmaf(v.z, wc[(k + 2) * 32], accA);
            accB = fmaf(v.w, wc[(k + 3) * 32], accB);
        }
        float hsv = fmaxf(accA + accB, 0.0f) * Wc2[j];
#pragma unroll
        for (int off = 16; off > 0; off >>= 1) hsv += __shfl_xor(hsv, off, 64);

        if (j == 0) {
            float logit = hsv + bc2[0];
            out[S0 + hh] = 1.0f / (1.0f + expf(-logit));
        }
    }
}

// ---------------------------------------------------------------------------
extern "C" void kernel_launch(void* const* d_in, const int* in_sizes, int n_in,
                              void* d_out, int out_size, void* d_ws, size_t ws_size,
                              hipStream_t stream)
{
    const float* lfeats = (const float*)d_in[0];
    const float* rfeats = (const float*)d_in[1];
    const int*   lseg   = (const int*)d_in[2];
    const int*   rseg   = (const int*)d_in[3];
    const float* W1     = (const float*)d_in[4];
    const float* b1     = (const float*)d_in[5];
    const float* Wc1    = (const float*)d_in[6];
    const float* bc1    = (const float*)d_in[7];
    const float* Wc2    = (const float*)d_in[8];
    const float* bc2    = (const float*)d_in[9];
    float* out = (float*)d_out;

    const int n  = in_sizes[2];        // N_UNITS per side (524288, %128 == 0)
    const int nw = n / UPW;            // waves per side (4096)

    // workspace layout (floats/ints):
    float* pooled = (float*)d_ws;                       // [16384][128]
    float* pFl = pooled + (size_t)BATCH_C * 128;        // [nw][64] each
    float* pLl = pFl + (size_t)nw * 64;
    float* pFr = pLl + (size_t)nw * 64;
    float* pLr = pFr + (size_t)nw * 64;
    int* lstart = (int*)(pLr + (size_t)nw * 64);        // [BATCH+16]
    int* rstart = lstart + (BATCH_C + 16);

    pool_dense<<<dim3(nw / 4, 2), 256, 0, stream>>>(
        lfeats, rfeats, lseg, rseg, lstart, rstart, W1, b1,
        pooled, pFl, pLl, pFr, pLr, n);

    head2_kernel<<<BATCH_C / 8, 256, 0, stream>>>(
        lstart, rstart, lseg, rseg, pooled, pFl, pLl, pFr, pLr,
        Wc1, bc1, Wc2, bc2, out);
}